// Round 4
// baseline (2298.095 us; speedup 1.0000x reference)
//
#include <hip/hip_runtime.h>
#include <hip/hip_bf16.h>
#include <stdint.h>

// Inputs may be float32 OR bf16 (detected at runtime on-device); internal
// canonical dtype is bf16; compute in fp32; output emitted in detected dtype.
typedef __bf16 bf16_t;
typedef __bf16 bf16x8 __attribute__((ext_vector_type(8)));
typedef float  f32x4  __attribute__((ext_vector_type(4)));

__device__ __forceinline__ f32x4 mfma16(bf16x8 a, bf16x8 b, f32x4 c) {
    // D[row=quad*4+r][col=lane&15]; A[row=lane&15][k=quad*8+j]; B[k=quad*8+j][col=lane&15]
    return __builtin_amdgcn_mfma_f32_16x16x32_bf16(a, b, c, 0, 0, 0);
}

__device__ __forceinline__ float ldv(const void* p, long i, int fp32mode) {
    return fp32mode ? ((const float*)p)[i] : (float)((const bf16_t*)p)[i];
}

// ---------------------------------------------------------------- dtype detect
// Reads first 4096 elements of x as bf16. If x is really fp32, the low halves
// of fp32 words have uniform-random exponents -> hundreds of |v|>1e6/NaN hits.
// If x is bf16 N(0,1), zero hits.  flag[0]=1 -> fp32 inputs; flag[1]=0 const.
__global__ __launch_bounds__(256)
void detect_dtype(const void* __restrict__ x, int* __restrict__ flag) {
    __shared__ int cnt;
    if (threadIdx.x == 0) cnt = 0;
    __syncthreads();
    const bf16_t* p = (const bf16_t*)x;
    int local = 0;
    for (int i = threadIdx.x; i < 4096; i += 256) {
        const float v = (float)p[i];
        if (!(fabsf(v) < 1e6f)) local++;   // catches NaN too
    }
    atomicAdd(&cnt, local);
    __syncthreads();
    if (threadIdx.x == 0) { flag[0] = (cnt >= 16) ? 1 : 0; flag[1] = 0; }
}

// ---------------------------------------------------------------- convert-transpose (batched)
__global__ __launch_bounds__(256)
void transpose_cvt(const void* __restrict__ in, bf16_t* __restrict__ out,
                   int R, int C, const int* __restrict__ flagp) {
    __shared__ bf16_t t[32][33];
    const int mode = *flagp;
    const long zi = (long)blockIdx.z * R * C;
    const int c0 = blockIdx.x * 32;
    const int r0 = blockIdx.y * 32;
    const int x  = threadIdx.x;
    const int y0 = threadIdx.y;
    for (int yy = y0; yy < 32; yy += 8)
        t[yy][x] = (bf16_t)ldv(in, zi + (long)(r0 + yy) * C + c0 + x, mode);
    __syncthreads();
    for (int yy = y0; yy < 32; yy += 8)
        out[zi + (long)(c0 + yy) * R + r0 + x] = t[x][yy];
}

// ---------------------------------------------------------------- layernorm (768 cols)
// dmodep: dtype of `in`; pmodep: dtype of gamma/beta. Output canonical bf16.
__global__ __launch_bounds__(256)
void ln768(const void* __restrict__ in, bf16_t* __restrict__ out,
           const void* __restrict__ gam, const void* __restrict__ bet,
           const int* __restrict__ dmodep, const int* __restrict__ pmodep) {
    __shared__ float rs[256], rq[256];
    const int dm = *dmodep, pm = *pmodep;
    const long base = (long)blockIdx.x * 768;
    const int tid = threadIdx.x;
    float v[3];
    float s = 0.f, q = 0.f;
#pragma unroll
    for (int i = 0; i < 3; ++i) {
        v[i] = ldv(in, base + i * 256 + tid, dm);
        s += v[i];
        q += v[i] * v[i];
    }
    rs[tid] = s; rq[tid] = q;
    __syncthreads();
    for (int st = 128; st > 0; st >>= 1) {
        if (tid < st) { rs[tid] += rs[tid + st]; rq[tid] += rq[tid + st]; }
        __syncthreads();
    }
    const float mean = rs[0] * (1.0f / 768.0f);
    const float var  = rq[0] * (1.0f / 768.0f) - mean * mean;
    const float rstd = rsqrtf(var + 1e-5f);
#pragma unroll
    for (int i = 0; i < 3; ++i) {
        const int c = i * 256 + tid;
        out[base + c] = (bf16_t)((v[i] - mean) * rstd * ldv(gam, c, pm) + ldv(bet, c, pm));
    }
}

// ---------------------------------------------------------------- MFMA GEMM: C = A * B^T
// A, B, C, res canonical bf16; bias raw input dtype (mode from flagp).
#define BM 128
#define BN 128
#define BK 64
#define LDT 72

__global__ __launch_bounds__(256)
void gemm_bt(const bf16_t* __restrict__ A, const bf16_t* __restrict__ B,
             bf16_t* __restrict__ C,
             int K, int lda, int ldb, int ldc,
             const void* __restrict__ bias, const int* __restrict__ flagp,
             const bf16_t* __restrict__ res, int do_relu) {
    __shared__ bf16_t As[BM][LDT];
    __shared__ bf16_t Bs[BN][LDT];
    const int bmode = *flagp;
    const int n0 = blockIdx.x * BN;
    const int m0 = blockIdx.y * BM;
    const bf16_t* Az = A + (long)m0 * lda;
    const bf16_t* Bz = B + (long)n0 * ldb;

    const int tid  = threadIdx.x;
    const int lane = tid & 63;
    const int w    = tid >> 6;
    const int wm   = (w >> 1) * 64;
    const int wn   = (w & 1) * 64;
    const int l15  = lane & 15;
    const int quad = lane >> 4;
    const int srow = tid >> 3;
    const int scol = (tid & 7) * 8;

    const f32x4 fz = {0.f, 0.f, 0.f, 0.f};
    f32x4 acc[4][4];
#pragma unroll
    for (int i = 0; i < 4; ++i)
#pragma unroll
        for (int j = 0; j < 4; ++j) acc[i][j] = fz;

    for (int k0 = 0; k0 < K; k0 += BK) {
        __syncthreads();
#pragma unroll
        for (int p = 0; p < 4; ++p) {
            const int r = srow + p * 32;
            *(bf16x8*)(&As[r][scol]) = *(const bf16x8*)(Az + (long)r * lda + k0 + scol);
            *(bf16x8*)(&Bs[r][scol]) = *(const bf16x8*)(Bz + (long)r * ldb + k0 + scol);
        }
        __syncthreads();
#pragma unroll
        for (int kk = 0; kk < BK; kk += 32) {
            bf16x8 af[4], bfr[4];
#pragma unroll
            for (int i = 0; i < 4; ++i)
                af[i] = *(const bf16x8*)(&As[wm + i * 16 + l15][kk + quad * 8]);
#pragma unroll
            for (int j = 0; j < 4; ++j)
                bfr[j] = *(const bf16x8*)(&Bs[wn + j * 16 + l15][kk + quad * 8]);
#pragma unroll
            for (int i = 0; i < 4; ++i)
#pragma unroll
                for (int j = 0; j < 4; ++j)
                    acc[i][j] = mfma16(af[i], bfr[j], acc[i][j]);
        }
    }

#pragma unroll
    for (int i = 0; i < 4; ++i) {
#pragma unroll
        for (int j = 0; j < 4; ++j) {
            const int mb = m0 + wm + i * 16 + quad * 4;
            const int nc = n0 + wn + j * 16 + l15;
#pragma unroll
            for (int r = 0; r < 4; ++r) {
                float v = acc[i][j][r];
                if (bias) v += ldv(bias, nc, bmode);
                if (do_relu) v = fmaxf(v, 0.0f);
                if (res) v += (float)res[(long)(mb + r) * ldc + nc];
                C[(long)(mb + r) * ldc + nc] = (bf16_t)v;
            }
        }
    }
}

// ---------------------------------------------------------------- fused attention
// Per (b, 16-row n-tile), loop 12 heads:
//   S = Q K^T / 8 (full M=1024 in regs across 8 waves, exact softmax)
//   P -> LDS;  T = P @ yn (via ynT);  O += T @ wv_h (via wvT)
// dx = O + sum_h bv_h;  h_pre = xn + dx.  HP may alias Q (block overwrites
// only its own 16 rows, after the last Q read).
__global__ __launch_bounds__(512)
void attn_fused(const bf16_t* __restrict__ Q, const bf16_t* __restrict__ Kp,
                const bf16_t* __restrict__ YNT, const bf16_t* __restrict__ WVT,
                const void* __restrict__ BV, const int* __restrict__ flagp,
                const bf16_t* __restrict__ XN, bf16_t* __restrict__ HP) {
    __shared__ bf16_t Pl[16][1032];
    __shared__ bf16_t Tl[16][776];
    __shared__ float  rmax[8][16];
    __shared__ float  rsum[8][16];

    const int bvmode = *flagp;
    const int b    = blockIdx.y;
    const int n0   = blockIdx.x * 16;
    const int tid  = threadIdx.x;
    const int w    = tid >> 6;
    const int lane = tid & 63;
    const int l15  = lane & 15;
    const int quad = lane >> 4;

    const f32x4 fz = {0.f, 0.f, 0.f, 0.f};
    f32x4 o[6];
#pragma unroll
    for (int g = 0; g < 6; ++g) o[g] = fz;

    float bvs[6];
#pragma unroll
    for (int g = 0; g < 6; ++g) {
        const int e = w * 96 + g * 16 + l15;
        float s = 0.f;
#pragma unroll
        for (int h = 0; h < 12; ++h) s += ldv(BV, h * 768 + e, bvmode);
        bvs[g] = s;
    }

    const long qoff  = (long)(b * 1024 + n0 + l15) * 768 + quad * 8;
    const long koff0 = (long)(b * 1024) * 768 + quad * 8;
    const long ynoff = (long)b * 768 * 1024;

#pragma unroll 1
    for (int h = 0; h < 12; ++h) {
        f32x4 s[8];
#pragma unroll
        for (int f = 0; f < 8; ++f) s[f] = fz;
        const bf16x8 qa0 = *(const bf16x8*)(Q + qoff + h * 64);
        const bf16x8 qa1 = *(const bf16x8*)(Q + qoff + h * 64 + 32);
#pragma unroll
        for (int f = 0; f < 8; ++f) {
            const int m = w * 128 + f * 16 + l15;
            const bf16_t* kp = Kp + koff0 + (long)m * 768 + h * 64;
            s[f] = mfma16(qa0, *(const bf16x8*)kp, s[f]);
            s[f] = mfma16(qa1, *(const bf16x8*)(kp + 32), s[f]);
        }
        float rm[4] = {-3e38f, -3e38f, -3e38f, -3e38f};
#pragma unroll
        for (int f = 0; f < 8; ++f)
#pragma unroll
            for (int r = 0; r < 4; ++r) {
                s[f][r] *= 0.125f;
                rm[r] = fmaxf(rm[r], s[f][r]);
            }
#pragma unroll
        for (int off = 1; off < 16; off <<= 1)
#pragma unroll
            for (int r = 0; r < 4; ++r) rm[r] = fmaxf(rm[r], __shfl_xor(rm[r], off));
        if (l15 == 0) {
#pragma unroll
            for (int r = 0; r < 4; ++r) rmax[w][quad * 4 + r] = rm[r];
        }
        __syncthreads();
        float gm[4];
#pragma unroll
        for (int r = 0; r < 4; ++r) {
            float mx = rmax[0][quad * 4 + r];
#pragma unroll
            for (int w2 = 1; w2 < 8; ++w2) mx = fmaxf(mx, rmax[w2][quad * 4 + r]);
            gm[r] = mx;
        }
        float ps[4] = {0.f, 0.f, 0.f, 0.f};
#pragma unroll
        for (int f = 0; f < 8; ++f)
#pragma unroll
            for (int r = 0; r < 4; ++r) {
                const float p = __expf(s[f][r] - gm[r]);
                s[f][r] = p;
                ps[r] += p;
            }
#pragma unroll
        for (int off = 1; off < 16; off <<= 1)
#pragma unroll
            for (int r = 0; r < 4; ++r) ps[r] += __shfl_xor(ps[r], off);
        if (l15 == 0) {
#pragma unroll
            for (int r = 0; r < 4; ++r) rsum[w][quad * 4 + r] = ps[r];
        }
        __syncthreads();
#pragma unroll
        for (int r = 0; r < 4; ++r) {
            float ss = 0.f;
#pragma unroll
            for (int w2 = 0; w2 < 8; ++w2) ss += rsum[w2][quad * 4 + r];
            gm[r] = 1.0f / ss;
        }
#pragma unroll
        for (int f = 0; f < 8; ++f)
#pragma unroll
            for (int r = 0; r < 4; ++r)
                Pl[quad * 4 + r][w * 128 + f * 16 + l15] = (bf16_t)(s[f][r] * gm[r]);
        __syncthreads();

        // T = P @ yn
        f32x4 t[6];
#pragma unroll
        for (int g = 0; g < 6; ++g) t[g] = fz;
        const bf16_t* yb0 = YNT + ynoff + (long)(w * 96 + l15) * 1024 + quad * 8;
#pragma unroll 4
        for (int ks = 0; ks < 32; ++ks) {
            const bf16x8 pa = *(const bf16x8*)(&Pl[l15][ks * 32 + quad * 8]);
#pragma unroll
            for (int g = 0; g < 6; ++g) {
                const bf16x8 yb = *(const bf16x8*)(yb0 + (long)g * 16 * 1024 + ks * 32);
                t[g] = mfma16(pa, yb, t[g]);
            }
        }
#pragma unroll
        for (int g = 0; g < 6; ++g)
#pragma unroll
            for (int r = 0; r < 4; ++r)
                Tl[quad * 4 + r][w * 96 + g * 16 + l15] = (bf16_t)t[g][r];
        __syncthreads();

        // O += T @ wv_h
        const bf16_t* vb0 = WVT + (long)(h * 768 + w * 96 + l15) * 768 + quad * 8;
#pragma unroll 4
        for (int ks = 0; ks < 24; ++ks) {
            const bf16x8 ta = *(const bf16x8*)(&Tl[l15][ks * 32 + quad * 8]);
#pragma unroll
            for (int g = 0; g < 6; ++g) {
                const bf16x8 vb = *(const bf16x8*)(vb0 + (long)g * 16 * 768 + ks * 32);
                o[g] = mfma16(ta, vb, o[g]);
            }
        }
        __syncthreads();
    }

    // epilogue: h_pre = xn + O + sum_h bv_h
#pragma unroll
    for (int g = 0; g < 6; ++g) {
#pragma unroll
        for (int r = 0; r < 4; ++r) {
            const int row  = n0 + quad * 4 + r;
            const int e    = w * 96 + g * 16 + l15;
            const long idx = (long)(b * 1024 + row) * 768 + e;
            HP[idx] = (bf16_t)(o[g][r] + bvs[g] + (float)XN[idx]);
        }
    }
}

// ---------------------------------------------------------------- output emit
__global__ __launch_bounds__(256)
void emit2(const bf16_t* __restrict__ a, const bf16_t* __restrict__ b,
           void* __restrict__ out, const int* __restrict__ flagp) {
    const int mode = *flagp;
    const long n = 6291456;
    const long stride = (long)gridDim.x * blockDim.x;
    for (long i = (long)blockIdx.x * blockDim.x + threadIdx.x; i < 2 * n; i += stride) {
        const bf16_t v = (i < n) ? a[i] : b[i - n];
        if (mode) ((float*)out)[i] = (float)v;
        else      ((bf16_t*)out)[i] = v;
    }
}

// ---------------------------------------------------------------- launch
extern "C" void kernel_launch(void* const* d_in, const int* in_sizes, int n_in,
                              void* d_out, int out_size, void* d_ws, size_t ws_size,
                              hipStream_t stream) {
    (void)in_sizes; (void)n_in; (void)out_size; (void)ws_size;

    const void* x    = d_in[0];
    const void* y    = d_in[1];
    const void* ln1g = d_in[2];
    const void* ln1b = d_in[3];
    const void* ln2g = d_in[4];
    const void* ln2b = d_in[5];
    const void* ln3g = d_in[6];
    const void* ln3b = d_in[7];
    const void* wq   = d_in[8];
    const void* bq   = d_in[9];
    const void* wk   = d_in[10];
    const void* bk   = d_in[11];
    const void* wv   = d_in[12];
    const void* bv   = d_in[13];
    const void* wi   = d_in[14];
    const void* bi   = d_in[15];
    const void* wo   = d_in[16];
    const void* bo   = d_in[17];

    // workspace layout (canonical bf16), ~81.8 MB
    char* ws = (char*)d_ws;
    bf16_t* xn   = (bf16_t*)(ws + 0);          // 12,582,912; reused as res0 after attn
    bf16_t* ynb  = (bf16_t*)(ws + 12582912);   // 12,582,912; live till emit (output 1)
    bf16_t* ynT  = (bf16_t*)(ws + 25165824);   // 12,582,912; reused as hn after attn
    bf16_t* qb   = (bf16_t*)(ws + 37748736);   // 12,582,912; Q then h_pre (in-place)
    bf16_t* kb   = (bf16_t*)(ws + 50331648);   // 12,582,912; reused as mid after attn
    bf16_t* wvT  = (bf16_t*)(ws + 62914560);   // 14,155,776
    bf16_t* wqT  = (bf16_t*)(ws + 77070336);   // 1,179,648
    bf16_t* wkT  = (bf16_t*)(ws + 78249984);
    bf16_t* wiT  = (bf16_t*)(ws + 79429632);
    bf16_t* woT  = (bf16_t*)(ws + 80609280);
    int*    flag = (int*)   (ws + 81788928);   // flag[0]=fp32 mode, flag[1]=0
    bf16_t* hn   = ynT;
    bf16_t* mid  = kb;
    bf16_t* res0 = xn;
    bf16_t* hpre = qb;
    const int* F  = flag;      // detected input dtype
    const int* Z  = flag + 1;  // constant 0 (canonical bf16)

    detect_dtype<<<1, 256, 0, stream>>>(x, flag);

    const dim3 tb(32, 8);
    transpose_cvt<<<dim3(24, 24, 1), tb, 0, stream>>>(wq, wqT, 768, 768, F);
    transpose_cvt<<<dim3(24, 24, 1), tb, 0, stream>>>(wk, wkT, 768, 768, F);
    transpose_cvt<<<dim3(288, 24, 1), tb, 0, stream>>>(wv, wvT, 768, 9216, F);
    transpose_cvt<<<dim3(24, 24, 1), tb, 0, stream>>>(wi, wiT, 768, 768, F);
    transpose_cvt<<<dim3(24, 24, 1), tb, 0, stream>>>(wo, woT, 768, 768, F);

    ln768<<<8192, 256, 0, stream>>>(x, xn, ln1g, ln1b, F, F);
    ln768<<<8192, 256, 0, stream>>>(y, ynb, ln2g, ln2b, F, F);
    transpose_cvt<<<dim3(24, 32, 8), tb, 0, stream>>>(ynb, ynT, 1024, 768, Z);

    // Q = xn @ wq + bq; K = yn @ wk + bk
    gemm_bt<<<dim3(6, 64), 256, 0, stream>>>(xn, wqT, qb, 768, 768, 768, 768,
                                             bq, F, nullptr, 0);
    gemm_bt<<<dim3(6, 64), 256, 0, stream>>>(ynb, wkT, kb, 768, 768, 768, 768,
                                             bk, F, nullptr, 0);

    attn_fused<<<dim3(64, 8), 512, 0, stream>>>(qb, kb, ynT, wvT, bv, F, xn, hpre);

    ln768<<<8192, 256, 0, stream>>>(hpre, hn, ln3g, ln3b, Z, F);

    gemm_bt<<<dim3(6, 64), 256, 0, stream>>>(hn, wiT, mid, 768, 768, 768, 768,
                                             bi, F, nullptr, 1);
    gemm_bt<<<dim3(6, 64), 256, 0, stream>>>(mid, woT, res0, 768, 768, 768, 768,
                                             bo, F, hn, 0);

    emit2<<<2048, 256, 0, stream>>>(res0, ynb, d_out, F);
}

// Round 5
// 1786.722 us; speedup vs baseline: 1.2862x; 1.2862x over previous
//
#include <hip/hip_runtime.h>
#include <hip/hip_bf16.h>
#include <stdint.h>

// Inputs may be float32 OR bf16 (detected at runtime on-device); internal
// canonical dtype is bf16; compute in fp32; output emitted in detected dtype.
typedef __bf16 bf16_t;
typedef __bf16 bf16x8 __attribute__((ext_vector_type(8)));
typedef float  f32x4  __attribute__((ext_vector_type(4)));

__device__ __forceinline__ f32x4 mfma16(bf16x8 a, bf16x8 b, f32x4 c) {
    // D[row=quad*4+r][col=lane&15]; A[row=lane&15][k=quad*8+j]; B[k=quad*8+j][col=lane&15]
    return __builtin_amdgcn_mfma_f32_16x16x32_bf16(a, b, c, 0, 0, 0);
}

__device__ __forceinline__ float ldv(const void* p, long i, int fp32mode) {
    return fp32mode ? ((const float*)p)[i] : (float)((const bf16_t*)p)[i];
}

// ---------------------------------------------------------------- dtype detect
__global__ __launch_bounds__(256)
void detect_dtype(const void* __restrict__ x, int* __restrict__ flag) {
    __shared__ int cnt;
    if (threadIdx.x == 0) cnt = 0;
    __syncthreads();
    const bf16_t* p = (const bf16_t*)x;
    int local = 0;
    for (int i = threadIdx.x; i < 4096; i += 256) {
        const float v = (float)p[i];
        if (!(fabsf(v) < 1e6f)) local++;   // catches NaN too
    }
    atomicAdd(&cnt, local);
    __syncthreads();
    if (threadIdx.x == 0) { flag[0] = (cnt >= 16) ? 1 : 0; flag[1] = 0; }
}

// ---------------------------------------------------------------- convert-transpose (batched)
__global__ __launch_bounds__(256)
void transpose_cvt(const void* __restrict__ in, bf16_t* __restrict__ out,
                   int R, int C, const int* __restrict__ flagp) {
    __shared__ bf16_t t[32][33];
    const int mode = *flagp;
    const long zi = (long)blockIdx.z * R * C;
    const int c0 = blockIdx.x * 32;
    const int r0 = blockIdx.y * 32;
    const int x  = threadIdx.x;
    const int y0 = threadIdx.y;
    for (int yy = y0; yy < 32; yy += 8)
        t[yy][x] = (bf16_t)ldv(in, zi + (long)(r0 + yy) * C + c0 + x, mode);
    __syncthreads();
    for (int yy = y0; yy < 32; yy += 8)
        out[zi + (long)(c0 + yy) * R + r0 + x] = t[x][yy];
}

// ---------------------------------------------------------------- wv permuted transpose
// W2T[e][h*768+k] = wv[k][h*768+e]   (both ld 9216)
__global__ __launch_bounds__(256)
void transpose_wv(const void* __restrict__ in, bf16_t* __restrict__ out,
                  const int* __restrict__ flagp) {
    __shared__ bf16_t t[32][33];
    const int mode = *flagp;
    const int h  = blockIdx.z;
    const int e0 = blockIdx.x * 32;
    const int k0 = blockIdx.y * 32;
    const int x  = threadIdx.x;
    const int y0 = threadIdx.y;
    for (int yy = y0; yy < 32; yy += 8)
        t[yy][x] = (bf16_t)ldv(in, (long)(k0 + yy) * 9216 + h * 768 + e0 + x, mode);
    __syncthreads();
    for (int yy = y0; yy < 32; yy += 8)
        out[(long)(e0 + yy) * 9216 + h * 768 + k0 + x] = t[x][yy];
}

// ---------------------------------------------------------------- bv head-sum
__global__ __launch_bounds__(256)
void bvsum_k(const void* __restrict__ bv, float* __restrict__ out,
             const int* __restrict__ flagp) {
    const int mode = *flagp;
    const int e = blockIdx.x * 256 + threadIdx.x;
    if (e < 768) {
        float s = 0.f;
#pragma unroll
        for (int h = 0; h < 12; ++h) s += ldv(bv, h * 768 + e, mode);
        out[e] = s;
    }
}

// ---------------------------------------------------------------- layernorm (768 cols)
__global__ __launch_bounds__(256)
void ln768(const void* __restrict__ in, bf16_t* __restrict__ out,
           const void* __restrict__ gam, const void* __restrict__ bet,
           const int* __restrict__ dmodep, const int* __restrict__ pmodep) {
    __shared__ float rs[256], rq[256];
    const int dm = *dmodep, pm = *pmodep;
    const long base = (long)blockIdx.x * 768;
    const int tid = threadIdx.x;
    float v[3];
    float s = 0.f, q = 0.f;
#pragma unroll
    for (int i = 0; i < 3; ++i) {
        v[i] = ldv(in, base + i * 256 + tid, dm);
        s += v[i];
        q += v[i] * v[i];
    }
    rs[tid] = s; rq[tid] = q;
    __syncthreads();
    for (int st = 128; st > 0; st >>= 1) {
        if (tid < st) { rs[tid] += rs[tid + st]; rq[tid] += rq[tid + st]; }
        __syncthreads();
    }
    const float mean = rs[0] * (1.0f / 768.0f);
    const float var  = rq[0] * (1.0f / 768.0f) - mean * mean;
    const float rstd = rsqrtf(var + 1e-5f);
#pragma unroll
    for (int i = 0; i < 3; ++i) {
        const int c = i * 256 + tid;
        out[base + c] = (bf16_t)((v[i] - mean) * rstd * ldv(gam, c, pm) + ldv(bet, c, pm));
    }
}

// ---------------------------------------------------------------- MFMA GEMM: C = A * B^T (bf16 out)
#define BM 128
#define BN 128
#define BK 64
#define LDT 72

__global__ __launch_bounds__(256)
void gemm_bt(const bf16_t* __restrict__ A, const bf16_t* __restrict__ B,
             bf16_t* __restrict__ C,
             int K, int lda, int ldb, int ldc,
             const void* __restrict__ bias, const int* __restrict__ flagp,
             const bf16_t* __restrict__ res, int do_relu) {
    __shared__ bf16_t As[BM][LDT];
    __shared__ bf16_t Bs[BN][LDT];
    const int bmode = *flagp;
    const int n0 = blockIdx.x * BN;
    const int m0 = blockIdx.y * BM;
    const bf16_t* Az = A + (long)m0 * lda;
    const bf16_t* Bz = B + (long)n0 * ldb;

    const int tid  = threadIdx.x;
    const int lane = tid & 63;
    const int w    = tid >> 6;
    const int wm   = (w >> 1) * 64;
    const int wn   = (w & 1) * 64;
    const int l15  = lane & 15;
    const int quad = lane >> 4;
    const int srow = tid >> 3;
    const int scol = (tid & 7) * 8;

    const f32x4 fz = {0.f, 0.f, 0.f, 0.f};
    f32x4 acc[4][4];
#pragma unroll
    for (int i = 0; i < 4; ++i)
#pragma unroll
        for (int j = 0; j < 4; ++j) acc[i][j] = fz;

    for (int k0 = 0; k0 < K; k0 += BK) {
        __syncthreads();
#pragma unroll
        for (int p = 0; p < 4; ++p) {
            const int r = srow + p * 32;
            *(bf16x8*)(&As[r][scol]) = *(const bf16x8*)(Az + (long)r * lda + k0 + scol);
            *(bf16x8*)(&Bs[r][scol]) = *(const bf16x8*)(Bz + (long)r * ldb + k0 + scol);
        }
        __syncthreads();
#pragma unroll
        for (int kk = 0; kk < BK; kk += 32) {
            bf16x8 af[4], bfr[4];
#pragma unroll
            for (int i = 0; i < 4; ++i)
                af[i] = *(const bf16x8*)(&As[wm + i * 16 + l15][kk + quad * 8]);
#pragma unroll
            for (int j = 0; j < 4; ++j)
                bfr[j] = *(const bf16x8*)(&Bs[wn + j * 16 + l15][kk + quad * 8]);
#pragma unroll
            for (int i = 0; i < 4; ++i)
#pragma unroll
                for (int j = 0; j < 4; ++j)
                    acc[i][j] = mfma16(af[i], bfr[j], acc[i][j]);
        }
    }

#pragma unroll
    for (int i = 0; i < 4; ++i) {
#pragma unroll
        for (int j = 0; j < 4; ++j) {
            const int mb = m0 + wm + i * 16 + quad * 4;
            const int nc = n0 + wn + j * 16 + l15;
#pragma unroll
            for (int r = 0; r < 4; ++r) {
                float v = acc[i][j][r];
                if (bias) v += ldv(bias, nc, bmode);
                if (do_relu) v = fmaxf(v, 0.0f);
                if (res) v += (float)res[(long)(mb + r) * ldc + nc];
                C[(long)(mb + r) * ldc + nc] = (bf16_t)v;
            }
        }
    }
}

// ---------------------------------------------------------------- MFMA GEMM accumulate: Cf32 (+)= A * B^T
__global__ __launch_bounds__(256)
void gemm_acc(const bf16_t* __restrict__ A, const bf16_t* __restrict__ B,
              float* __restrict__ C,
              int K, int lda, int ldb, int ldc, int first) {
    __shared__ bf16_t As[BM][LDT];
    __shared__ bf16_t Bs[BN][LDT];
    const int n0 = blockIdx.x * BN;
    const int m0 = blockIdx.y * BM;
    const bf16_t* Az = A + (long)m0 * lda;
    const bf16_t* Bz = B + (long)n0 * ldb;

    const int tid  = threadIdx.x;
    const int lane = tid & 63;
    const int w    = tid >> 6;
    const int wm   = (w >> 1) * 64;
    const int wn   = (w & 1) * 64;
    const int l15  = lane & 15;
    const int quad = lane >> 4;
    const int srow = tid >> 3;
    const int scol = (tid & 7) * 8;

    const f32x4 fz = {0.f, 0.f, 0.f, 0.f};
    f32x4 acc[4][4];
#pragma unroll
    for (int i = 0; i < 4; ++i)
#pragma unroll
        for (int j = 0; j < 4; ++j) acc[i][j] = fz;

    for (int k0 = 0; k0 < K; k0 += BK) {
        __syncthreads();
#pragma unroll
        for (int p = 0; p < 4; ++p) {
            const int r = srow + p * 32;
            *(bf16x8*)(&As[r][scol]) = *(const bf16x8*)(Az + (long)r * lda + k0 + scol);
            *(bf16x8*)(&Bs[r][scol]) = *(const bf16x8*)(Bz + (long)r * ldb + k0 + scol);
        }
        __syncthreads();
#pragma unroll
        for (int kk = 0; kk < BK; kk += 32) {
            bf16x8 af[4], bfr[4];
#pragma unroll
            for (int i = 0; i < 4; ++i)
                af[i] = *(const bf16x8*)(&As[wm + i * 16 + l15][kk + quad * 8]);
#pragma unroll
            for (int j = 0; j < 4; ++j)
                bfr[j] = *(const bf16x8*)(&Bs[wn + j * 16 + l15][kk + quad * 8]);
#pragma unroll
            for (int i = 0; i < 4; ++i)
#pragma unroll
                for (int j = 0; j < 4; ++j)
                    acc[i][j] = mfma16(af[i], bfr[j], acc[i][j]);
        }
    }

#pragma unroll
    for (int i = 0; i < 4; ++i) {
#pragma unroll
        for (int j = 0; j < 4; ++j) {
            const int mb = m0 + wm + i * 16 + quad * 4;
            const int nc = n0 + wn + j * 16 + l15;
#pragma unroll
            for (int r = 0; r < 4; ++r) {
                float* cp = C + (long)(mb + r) * ldc + nc;
                float v = acc[i][j][r];
                if (!first) v += *cp;
                *cp = v;
            }
        }
    }
}

// ---------------------------------------------------------------- fused S->softmax->T kernel
// Per (b, 32-row n-tile), loop 4 heads of group hg:
//   S = Q K^T / 8 (full M=1024 in regs; 2 row-groups x 8 col-waves)
//   exact softmax; P -> LDS; T_h = P @ yn (via ynT) -> global Tb
// Tb layout: [b*1024+n][hl*768 + k], ld 3072.
// Grid x: b = x&7 (XCD co-location of same-b blocks), ntile = x>>3.
__global__ __launch_bounds__(1024, 4)
void fused_T(const bf16_t* __restrict__ Q, const bf16_t* __restrict__ Kp,
             const bf16_t* __restrict__ YNT, bf16_t* __restrict__ Tb, int hg) {
    __shared__ bf16_t Pl[32][1032];
    __shared__ float  rmax[2][8][16];
    __shared__ float  rsum[2][8][16];

    const int bx   = blockIdx.x;
    const int b    = bx & 7;
    const int n0   = (bx >> 3) * 32;
    const int tid  = threadIdx.x;
    const int w    = tid >> 6;          // 0..15
    const int rg   = w >> 3;            // row-group 0/1 (16 rows each)
    const int wc   = w & 7;             // col-wave 0..7
    const int lane = tid & 63;
    const int l15  = lane & 15;
    const int quad = lane >> 4;

    const f32x4 fz = {0.f, 0.f, 0.f, 0.f};
    const long qoff  = (long)(b * 1024 + n0 + rg * 16 + l15) * 768 + quad * 8;
    const long koff0 = (long)(b * 1024) * 768 + quad * 8;
    const long ynoff = (long)b * 768 * 1024;
    const long trow0 = (long)(b * 1024 + n0 + rg * 16);

#pragma unroll 1
    for (int hl = 0; hl < 4; ++hl) {
        const int h = hg * 4 + hl;
        // ---- S = Q K^T: this wave covers rows [rg*16,+16), cols m = wc*128 + f*16 + l15
        f32x4 s[8];
#pragma unroll
        for (int f = 0; f < 8; ++f) s[f] = fz;
        const bf16x8 qa0 = *(const bf16x8*)(Q + qoff + h * 64);
        const bf16x8 qa1 = *(const bf16x8*)(Q + qoff + h * 64 + 32);
#pragma unroll
        for (int f = 0; f < 8; ++f) {
            const int m = wc * 128 + f * 16 + l15;
            const bf16_t* kp = Kp + koff0 + (long)m * 768 + h * 64;
            s[f] = mfma16(qa0, *(const bf16x8*)kp, s[f]);
            s[f] = mfma16(qa1, *(const bf16x8*)(kp + 32), s[f]);
        }
        // ---- softmax over m; lane owns rows rg*16 + quad*4 + r
        float rm[4] = {-3e38f, -3e38f, -3e38f, -3e38f};
#pragma unroll
        for (int f = 0; f < 8; ++f)
#pragma unroll
            for (int r = 0; r < 4; ++r) {
                s[f][r] *= 0.125f;
                rm[r] = fmaxf(rm[r], s[f][r]);
            }
#pragma unroll
        for (int off = 1; off < 16; off <<= 1)
#pragma unroll
            for (int r = 0; r < 4; ++r) rm[r] = fmaxf(rm[r], __shfl_xor(rm[r], off));
        if (l15 == 0) {
#pragma unroll
            for (int r = 0; r < 4; ++r) rmax[rg][wc][quad * 4 + r] = rm[r];
        }
        __syncthreads();
        float gm[4];
#pragma unroll
        for (int r = 0; r < 4; ++r) {
            float mx = rmax[rg][0][quad * 4 + r];
#pragma unroll
            for (int w2 = 1; w2 < 8; ++w2) mx = fmaxf(mx, rmax[rg][w2][quad * 4 + r]);
            gm[r] = mx;
        }
        float ps[4] = {0.f, 0.f, 0.f, 0.f};
#pragma unroll
        for (int f = 0; f < 8; ++f)
#pragma unroll
            for (int r = 0; r < 4; ++r) {
                const float p = __expf(s[f][r] - gm[r]);
                s[f][r] = p;
                ps[r] += p;
            }
#pragma unroll
        for (int off = 1; off < 16; off <<= 1)
#pragma unroll
            for (int r = 0; r < 4; ++r) ps[r] += __shfl_xor(ps[r], off);
        if (l15 == 0) {
#pragma unroll
            for (int r = 0; r < 4; ++r) rsum[rg][wc][quad * 4 + r] = ps[r];
        }
        __syncthreads();
#pragma unroll
        for (int r = 0; r < 4; ++r) {
            float ss = 0.f;
#pragma unroll
            for (int w2 = 0; w2 < 8; ++w2) ss += rsum[rg][w2][quad * 4 + r];
            gm[r] = 1.0f / ss;
        }
#pragma unroll
        for (int f = 0; f < 8; ++f)
#pragma unroll
            for (int r = 0; r < 4; ++r)
                Pl[rg * 16 + quad * 4 + r][wc * 128 + f * 16 + l15] = (bf16_t)(s[f][r] * gm[r]);
        __syncthreads();

        // ---- T_h = P @ yn : row-group rg, this wave owns cols [wc*96, +96); K-dim = m
        f32x4 t[6];
#pragma unroll
        for (int g = 0; g < 6; ++g) t[g] = fz;
        const bf16_t* yb0 = YNT + ynoff + (long)(wc * 96 + l15) * 1024 + quad * 8;
#pragma unroll 4
        for (int ks = 0; ks < 32; ++ks) {
            const bf16x8 pa = *(const bf16x8*)(&Pl[rg * 16 + l15][ks * 32 + quad * 8]);
#pragma unroll
            for (int g = 0; g < 6; ++g) {
                const bf16x8 yb = *(const bf16x8*)(yb0 + (long)g * 16 * 1024 + ks * 32);
                t[g] = mfma16(pa, yb, t[g]);
            }
        }
        // write T to global: Tb[trow0 + quad*4 + r][hl*768 + wc*96 + g*16 + l15]
#pragma unroll
        for (int g = 0; g < 6; ++g)
#pragma unroll
            for (int r = 0; r < 4; ++r)
                Tb[(trow0 + quad * 4 + r) * 3072 + hl * 768 + wc * 96 + g * 16 + l15] =
                    (bf16_t)t[g][r];
        __syncthreads();   // before next head overwrites Pl/rmax/rsum
    }
}

// ---------------------------------------------------------------- h_pre epilogue
__global__ __launch_bounds__(256)
void hpre_ep(const float* __restrict__ dx, const float* __restrict__ bvs,
             const bf16_t* __restrict__ xn, bf16_t* __restrict__ hp) {
    const long i = (long)blockIdx.x * 256 + threadIdx.x;   // grid covers 6291456
    const int e = (int)(i % 768);
    hp[i] = (bf16_t)(dx[i] + bvs[e] + (float)xn[i]);
}

// ---------------------------------------------------------------- output emit
__global__ __launch_bounds__(256)
void emit2(const bf16_t* __restrict__ a, const bf16_t* __restrict__ b,
           void* __restrict__ out, const int* __restrict__ flagp) {
    const int mode = *flagp;
    const long n = 6291456;
    const long stride = (long)gridDim.x * blockDim.x;
    for (long i = (long)blockIdx.x * blockDim.x + threadIdx.x; i < 2 * n; i += stride) {
        const bf16_t v = (i < n) ? a[i] : b[i - n];
        if (mode) ((float*)out)[i] = (float)v;
        else      ((bf16_t*)out)[i] = v;
    }
}

// ---------------------------------------------------------------- launch
extern "C" void kernel_launch(void* const* d_in, const int* in_sizes, int n_in,
                              void* d_out, int out_size, void* d_ws, size_t ws_size,
                              hipStream_t stream) {
    (void)in_sizes; (void)n_in; (void)out_size; (void)ws_size;

    const void* x    = d_in[0];
    const void* y    = d_in[1];
    const void* ln1g = d_in[2];
    const void* ln1b = d_in[3];
    const void* ln2g = d_in[4];
    const void* ln2b = d_in[5];
    const void* ln3g = d_in[6];
    const void* ln3b = d_in[7];
    const void* wq   = d_in[8];
    const void* bq   = d_in[9];
    const void* wk   = d_in[10];
    const void* bk   = d_in[11];
    const void* wv   = d_in[12];
    const void* bv   = d_in[13];
    const void* wi   = d_in[14];
    const void* bi   = d_in[15];
    const void* wo   = d_in[16];
    const void* bo   = d_in[17];

    // workspace layout (canonical bf16 unless noted), ~157.3 MB
    char* ws = (char*)d_ws;
    bf16_t* xn    = (bf16_t*)(ws + 0);           // 12,582,912
    bf16_t* ynb   = (bf16_t*)(ws + 12582912);    // 12,582,912 (output 1, kept till emit)
    bf16_t* ynT   = (bf16_t*)(ws + 25165824);    // 12,582,912
    bf16_t* qb    = (bf16_t*)(ws + 37748736);    // 12,582,912 (Q; later h_pre)
    bf16_t* kb    = (bf16_t*)(ws + 50331648);    // 12,582,912 (K; later hn)
    bf16_t* Tbuf  = (bf16_t*)(ws + 62914560);    // 8192 x 3072 = 50,331,648 (later mid)
    float*  dxf   = (float*) (ws + 113246208);   // 8192 x 768 x 4 = 25,165,824
    bf16_t* W2T   = (bf16_t*)(ws + 138412032);   // 768 x 9216 = 14,155,776
    bf16_t* wqT   = (bf16_t*)(ws + 152567808);   // 1,179,648
    bf16_t* wkT   = (bf16_t*)(ws + 153747456);
    bf16_t* wiT   = (bf16_t*)(ws + 154927104);
    bf16_t* woT   = (bf16_t*)(ws + 156106752);
    float*  bvs   = (float*) (ws + 157286400);   // 3,072
    int*    flag  = (int*)   (ws + 157290496);   // flag[0]=fp32 mode, flag[1]=0
    bf16_t* hpre  = qb;
    bf16_t* hn    = kb;
    bf16_t* mid   = Tbuf;
    bf16_t* res0  = xn;
    const int* F  = flag;
    const int* Z  = flag + 1;

    detect_dtype<<<1, 256, 0, stream>>>(x, flag);

    const dim3 tb(32, 8);
    transpose_cvt<<<dim3(24, 24, 1), tb, 0, stream>>>(wq, wqT, 768, 768, F);
    transpose_cvt<<<dim3(24, 24, 1), tb, 0, stream>>>(wk, wkT, 768, 768, F);
    transpose_cvt<<<dim3(24, 24, 1), tb, 0, stream>>>(wi, wiT, 768, 768, F);
    transpose_cvt<<<dim3(24, 24, 1), tb, 0, stream>>>(wo, woT, 768, 768, F);
    transpose_wv<<<dim3(24, 24, 12), tb, 0, stream>>>(wv, W2T, F);
    bvsum_k<<<3, 256, 0, stream>>>(bv, bvs, F);

    ln768<<<8192, 256, 0, stream>>>(x, xn, ln1g, ln1b, F, F);
    ln768<<<8192, 256, 0, stream>>>(y, ynb, ln2g, ln2b, F, F);
    transpose_cvt<<<dim3(24, 32, 8), tb, 0, stream>>>(ynb, ynT, 1024, 768, Z);

    // Q = xn @ wq + bq; K = yn @ wk + bk
    gemm_bt<<<dim3(6, 64), 256, 0, stream>>>(xn, wqT, qb, 768, 768, 768, 768,
                                             bq, F, nullptr, 0);
    gemm_bt<<<dim3(6, 64), 256, 0, stream>>>(ynb, wkT, kb, 768, 768, 768, 768,
                                             bk, F, nullptr, 0);

    // attention in 3 head-groups of 4: T = P@yn, then dx (+)= T @ W2^T
    for (int hg = 0; hg < 3; ++hg) {
        fused_T<<<256, 1024, 0, stream>>>(qb, kb, ynT, Tbuf, hg);
        gemm_acc<<<dim3(6, 64), 256, 0, stream>>>(Tbuf, W2T + hg * 3072, dxf,
                                                  3072, 3072, 9216, 768, hg == 0);
    }

    // h_pre = xn + dx + sum_h bv_h   (qb dead -> reuse)
    hpre_ep<<<24576, 256, 0, stream>>>(dxf, bvs, xn, hpre);

    ln768<<<8192, 256, 0, stream>>>(hpre, hn, ln3g, ln3b, Z, F);

    gemm_bt<<<dim3(6, 64), 256, 0, stream>>>(hn, wiT, mid, 768, 768, 768, 768,
                                             bi, F, nullptr, 1);
    gemm_bt<<<dim3(6, 64), 256, 0, stream>>>(mid, woT, res0, 768, 768, 768, 768,
                                             bo, F, hn, 0);

    emit2<<<2048, 256, 0, stream>>>(res0, ynb, d_out, F);
}

// Round 6
// 1764.687 us; speedup vs baseline: 1.3023x; 1.0125x over previous
//
#include <hip/hip_runtime.h>
#include <hip/hip_bf16.h>
#include <stdint.h>

// Inputs may be float32 OR bf16 (detected at runtime on-device); internal
// canonical dtype is bf16; compute in fp32; output emitted in detected dtype.
typedef __bf16 bf16_t;
typedef __bf16 bf16x8 __attribute__((ext_vector_type(8)));
typedef float  f32x4  __attribute__((ext_vector_type(4)));

__device__ __forceinline__ f32x4 mfma16(bf16x8 a, bf16x8 b, f32x4 c) {
    // D[row=quad*4+r][col=lane&15]; A[row=lane&15][k=quad*8+j]; B[k=quad*8+j][col=lane&15]
    return __builtin_amdgcn_mfma_f32_16x16x32_bf16(a, b, c, 0, 0, 0);
}

__device__ __forceinline__ float ldv(const void* p, long i, int fp32mode) {
    return fp32mode ? ((const float*)p)[i] : (float)((const bf16_t*)p)[i];
}

// ---------------------------------------------------------------- dtype detect
__global__ __launch_bounds__(256)
void detect_dtype(const void* __restrict__ x, int* __restrict__ flag) {
    __shared__ int cnt;
    if (threadIdx.x == 0) cnt = 0;
    __syncthreads();
    const bf16_t* p = (const bf16_t*)x;
    int local = 0;
    for (int i = threadIdx.x; i < 4096; i += 256) {
        const float v = (float)p[i];
        if (!(fabsf(v) < 1e6f)) local++;   // catches NaN too
    }
    atomicAdd(&cnt, local);
    __syncthreads();
    if (threadIdx.x == 0) { flag[0] = (cnt >= 16) ? 1 : 0; flag[1] = 0; }
}

// ---------------------------------------------------------------- convert-transpose (batched)
__global__ __launch_bounds__(256)
void transpose_cvt(const void* __restrict__ in, bf16_t* __restrict__ out,
                   int R, int C, const int* __restrict__ flagp) {
    __shared__ bf16_t t[32][33];
    const int mode = *flagp;
    const long zi = (long)blockIdx.z * R * C;
    const int c0 = blockIdx.x * 32;
    const int r0 = blockIdx.y * 32;
    const int x  = threadIdx.x;
    const int y0 = threadIdx.y;
    for (int yy = y0; yy < 32; yy += 8)
        t[yy][x] = (bf16_t)ldv(in, zi + (long)(r0 + yy) * C + c0 + x, mode);
    __syncthreads();
    for (int yy = y0; yy < 32; yy += 8)
        out[zi + (long)(c0 + yy) * R + r0 + x] = t[x][yy];
}

// ---------------------------------------------------------------- wv permuted transpose
// W2T[e][h*768+k] = wv[k][h*768+e]   (both ld 9216)
__global__ __launch_bounds__(256)
void transpose_wv(const void* __restrict__ in, bf16_t* __restrict__ out,
                  const int* __restrict__ flagp) {
    __shared__ bf16_t t[32][33];
    const int mode = *flagp;
    const int h  = blockIdx.z;
    const int e0 = blockIdx.x * 32;
    const int k0 = blockIdx.y * 32;
    const int x  = threadIdx.x;
    const int y0 = threadIdx.y;
    for (int yy = y0; yy < 32; yy += 8)
        t[yy][x] = (bf16_t)ldv(in, (long)(k0 + yy) * 9216 + h * 768 + e0 + x, mode);
    __syncthreads();
    for (int yy = y0; yy < 32; yy += 8)
        out[(long)(e0 + yy) * 9216 + h * 768 + k0 + x] = t[x][yy];
}

// ---------------------------------------------------------------- bv head-sum
__global__ __launch_bounds__(256)
void bvsum_k(const void* __restrict__ bv, float* __restrict__ out,
             const int* __restrict__ flagp) {
    const int mode = *flagp;
    const int e = blockIdx.x * 256 + threadIdx.x;
    if (e < 768) {
        float s = 0.f;
#pragma unroll
        for (int h = 0; h < 12; ++h) s += ldv(bv, h * 768 + e, mode);
        out[e] = s;
    }
}

// ---------------------------------------------------------------- layernorm (768 cols)
__global__ __launch_bounds__(256)
void ln768(const void* __restrict__ in, bf16_t* __restrict__ out,
           const void* __restrict__ gam, const void* __restrict__ bet,
           const int* __restrict__ dmodep, const int* __restrict__ pmodep) {
    __shared__ float rs[256], rq[256];
    const int dm = *dmodep, pm = *pmodep;
    const long base = (long)blockIdx.x * 768;
    const int tid = threadIdx.x;
    float v[3];
    float s = 0.f, q = 0.f;
#pragma unroll
    for (int i = 0; i < 3; ++i) {
        v[i] = ldv(in, base + i * 256 + tid, dm);
        s += v[i];
        q += v[i] * v[i];
    }
    rs[tid] = s; rq[tid] = q;
    __syncthreads();
    for (int st = 128; st > 0; st >>= 1) {
        if (tid < st) { rs[tid] += rs[tid + st]; rq[tid] += rq[tid + st]; }
        __syncthreads();
    }
    const float mean = rs[0] * (1.0f / 768.0f);
    const float var  = rq[0] * (1.0f / 768.0f) - mean * mean;
    const float rstd = rsqrtf(var + 1e-5f);
#pragma unroll
    for (int i = 0; i < 3; ++i) {
        const int c = i * 256 + tid;
        out[base + c] = (bf16_t)((v[i] - mean) * rstd * ldv(gam, c, pm) + ldv(bet, c, pm));
    }
}

// ---------------------------------------------------------------- MFMA GEMM: C = A * B^T (bf16 out)
#define BM 128
#define BN 128
#define BK 64
#define LDT 72

__global__ __launch_bounds__(256)
void gemm_bt(const bf16_t* __restrict__ A, const bf16_t* __restrict__ B,
             bf16_t* __restrict__ C,
             int K, int lda, int ldb, int ldc,
             const void* __restrict__ bias, const int* __restrict__ flagp,
             const bf16_t* __restrict__ res, int do_relu) {
    __shared__ bf16_t As[BM][LDT];
    __shared__ bf16_t Bs[BN][LDT];
    const int bmode = *flagp;
    const int n0 = blockIdx.x * BN;
    const int m0 = blockIdx.y * BM;
    const bf16_t* Az = A + (long)m0 * lda;
    const bf16_t* Bz = B + (long)n0 * ldb;

    const int tid  = threadIdx.x;
    const int lane = tid & 63;
    const int w    = tid >> 6;
    const int wm   = (w >> 1) * 64;
    const int wn   = (w & 1) * 64;
    const int l15  = lane & 15;
    const int quad = lane >> 4;
    const int srow = tid >> 3;
    const int scol = (tid & 7) * 8;

    const f32x4 fz = {0.f, 0.f, 0.f, 0.f};
    f32x4 acc[4][4];
#pragma unroll
    for (int i = 0; i < 4; ++i)
#pragma unroll
        for (int j = 0; j < 4; ++j) acc[i][j] = fz;

    for (int k0 = 0; k0 < K; k0 += BK) {
        __syncthreads();
#pragma unroll
        for (int p = 0; p < 4; ++p) {
            const int r = srow + p * 32;
            *(bf16x8*)(&As[r][scol]) = *(const bf16x8*)(Az + (long)r * lda + k0 + scol);
            *(bf16x8*)(&Bs[r][scol]) = *(const bf16x8*)(Bz + (long)r * ldb + k0 + scol);
        }
        __syncthreads();
#pragma unroll
        for (int kk = 0; kk < BK; kk += 32) {
            bf16x8 af[4], bfr[4];
#pragma unroll
            for (int i = 0; i < 4; ++i)
                af[i] = *(const bf16x8*)(&As[wm + i * 16 + l15][kk + quad * 8]);
#pragma unroll
            for (int j = 0; j < 4; ++j)
                bfr[j] = *(const bf16x8*)(&Bs[wn + j * 16 + l15][kk + quad * 8]);
#pragma unroll
            for (int i = 0; i < 4; ++i)
#pragma unroll
                for (int j = 0; j < 4; ++j)
                    acc[i][j] = mfma16(af[i], bfr[j], acc[i][j]);
        }
    }

#pragma unroll
    for (int i = 0; i < 4; ++i) {
#pragma unroll
        for (int j = 0; j < 4; ++j) {
            const int mb = m0 + wm + i * 16 + quad * 4;
            const int nc = n0 + wn + j * 16 + l15;
#pragma unroll
            for (int r = 0; r < 4; ++r) {
                float v = acc[i][j][r];
                if (bias) v += ldv(bias, nc, bmode);
                if (do_relu) v = fmaxf(v, 0.0f);
                if (res) v += (float)res[(long)(mb + r) * ldc + nc];
                C[(long)(mb + r) * ldc + nc] = (bf16_t)v;
            }
        }
    }
}

// ---------------------------------------------------------------- MFMA GEMM accumulate: Cf32 (+)= A * B^T
__global__ __launch_bounds__(256)
void gemm_acc(const bf16_t* __restrict__ A, const bf16_t* __restrict__ B,
              float* __restrict__ C,
              int K, int lda, int ldb, int ldc, int first) {
    __shared__ bf16_t As[BM][LDT];
    __shared__ bf16_t Bs[BN][LDT];
    const int n0 = blockIdx.x * BN;
    const int m0 = blockIdx.y * BM;
    const bf16_t* Az = A + (long)m0 * lda;
    const bf16_t* Bz = B + (long)n0 * ldb;

    const int tid  = threadIdx.x;
    const int lane = tid & 63;
    const int w    = tid >> 6;
    const int wm   = (w >> 1) * 64;
    const int wn   = (w & 1) * 64;
    const int l15  = lane & 15;
    const int quad = lane >> 4;
    const int srow = tid >> 3;
    const int scol = (tid & 7) * 8;

    const f32x4 fz = {0.f, 0.f, 0.f, 0.f};
    f32x4 acc[4][4];
#pragma unroll
    for (int i = 0; i < 4; ++i)
#pragma unroll
        for (int j = 0; j < 4; ++j) acc[i][j] = fz;

    for (int k0 = 0; k0 < K; k0 += BK) {
        __syncthreads();
#pragma unroll
        for (int p = 0; p < 4; ++p) {
            const int r = srow + p * 32;
            *(bf16x8*)(&As[r][scol]) = *(const bf16x8*)(Az + (long)r * lda + k0 + scol);
            *(bf16x8*)(&Bs[r][scol]) = *(const bf16x8*)(Bz + (long)r * ldb + k0 + scol);
        }
        __syncthreads();
#pragma unroll
        for (int kk = 0; kk < BK; kk += 32) {
            bf16x8 af[4], bfr[4];
#pragma unroll
            for (int i = 0; i < 4; ++i)
                af[i] = *(const bf16x8*)(&As[wm + i * 16 + l15][kk + quad * 8]);
#pragma unroll
            for (int j = 0; j < 4; ++j)
                bfr[j] = *(const bf16x8*)(&Bs[wn + j * 16 + l15][kk + quad * 8]);
#pragma unroll
            for (int i = 0; i < 4; ++i)
#pragma unroll
                for (int j = 0; j < 4; ++j)
                    acc[i][j] = mfma16(af[i], bfr[j], acc[i][j]);
        }
    }

#pragma unroll
    for (int i = 0; i < 4; ++i) {
#pragma unroll
        for (int j = 0; j < 4; ++j) {
            const int mb = m0 + wm + i * 16 + quad * 4;
            const int nc = n0 + wn + j * 16 + l15;
#pragma unroll
            for (int r = 0; r < 4; ++r) {
                float* cp = C + (long)(mb + r) * ldc + nc;
                float v = acc[i][j][r];
                if (!first) v += *cp;
                *cp = v;
            }
        }
    }
}

// ---------------------------------------------------------------- fused S->softmax->T kernel
// Per (b, 16-row n-tile, head-pair hs), loop 2 heads of group hg:
//   S = Q K^T / 8 (full M=1024 in regs; 8 col-waves), exact softmax,
//   P -> LDS, T_h = P @ yn (via ynT) -> global Tb.
// Tb layout: [b*1024+n][hl*768 + k], ld 3072 (4 heads per group).
// Grid x = 1024: b = x&7 (XCD co-location), nt = (x>>3)&63, hs = x>>9.
// 8 waves, LDS 34 KB -> 4 blocks/CU, 32 waves/CU (round-5 had 16: latency fix).
__global__ __launch_bounds__(512, 8)
void fused_T(const bf16_t* __restrict__ Q, const bf16_t* __restrict__ Kp,
             const bf16_t* __restrict__ YNT, bf16_t* __restrict__ Tb, int hg) {
    __shared__ bf16_t Pl[16][1032];
    __shared__ float  rmax[8][16];
    __shared__ float  rsum[8][16];

    const int bx   = blockIdx.x;
    const int b    = bx & 7;
    const int n0   = ((bx >> 3) & 63) * 16;
    const int hs   = bx >> 9;           // 0/1: head-pair within group
    const int tid  = threadIdx.x;
    const int w    = tid >> 6;          // 0..7 col-waves
    const int lane = tid & 63;
    const int l15  = lane & 15;
    const int quad = lane >> 4;

    const f32x4 fz = {0.f, 0.f, 0.f, 0.f};
    const long qoff  = (long)(b * 1024 + n0 + l15) * 768 + quad * 8;
    const long koff0 = (long)(b * 1024) * 768 + quad * 8;
    const long ynoff = (long)b * 768 * 1024;
    const long trow0 = (long)(b * 1024 + n0);

#pragma unroll 1
    for (int hp = 0; hp < 2; ++hp) {
        const int hl = hs * 2 + hp;     // 0..3 within group
        const int h  = hg * 4 + hl;     // global head
        // ---- S = Q K^T: this wave covers cols m = w*128 + f*16 + l15
        f32x4 s[8];
#pragma unroll
        for (int f = 0; f < 8; ++f) s[f] = fz;
        const bf16x8 qa0 = *(const bf16x8*)(Q + qoff + h * 64);
        const bf16x8 qa1 = *(const bf16x8*)(Q + qoff + h * 64 + 32);
#pragma unroll
        for (int f = 0; f < 8; ++f) {
            const int m = w * 128 + f * 16 + l15;
            const bf16_t* kp = Kp + koff0 + (long)m * 768 + h * 64;
            s[f] = mfma16(qa0, *(const bf16x8*)kp, s[f]);
            s[f] = mfma16(qa1, *(const bf16x8*)(kp + 32), s[f]);
        }
        // ---- softmax over m; lane owns rows quad*4 + r
        float rm[4] = {-3e38f, -3e38f, -3e38f, -3e38f};
#pragma unroll
        for (int f = 0; f < 8; ++f)
#pragma unroll
            for (int r = 0; r < 4; ++r) {
                s[f][r] *= 0.125f;
                rm[r] = fmaxf(rm[r], s[f][r]);
            }
#pragma unroll
        for (int off = 1; off < 16; off <<= 1)
#pragma unroll
            for (int r = 0; r < 4; ++r) rm[r] = fmaxf(rm[r], __shfl_xor(rm[r], off));
        if (l15 == 0) {
#pragma unroll
            for (int r = 0; r < 4; ++r) rmax[w][quad * 4 + r] = rm[r];
        }
        __syncthreads();
        float gm[4];
#pragma unroll
        for (int r = 0; r < 4; ++r) {
            float mx = rmax[0][quad * 4 + r];
#pragma unroll
            for (int w2 = 1; w2 < 8; ++w2) mx = fmaxf(mx, rmax[w2][quad * 4 + r]);
            gm[r] = mx;
        }
        float ps[4] = {0.f, 0.f, 0.f, 0.f};
#pragma unroll
        for (int f = 0; f < 8; ++f)
#pragma unroll
            for (int r = 0; r < 4; ++r) {
                const float p = __expf(s[f][r] - gm[r]);
                s[f][r] = p;
                ps[r] += p;
            }
#pragma unroll
        for (int off = 1; off < 16; off <<= 1)
#pragma unroll
            for (int r = 0; r < 4; ++r) ps[r] += __shfl_xor(ps[r], off);
        if (l15 == 0) {
#pragma unroll
            for (int r = 0; r < 4; ++r) rsum[w][quad * 4 + r] = ps[r];
        }
        __syncthreads();
#pragma unroll
        for (int r = 0; r < 4; ++r) {
            float ss = 0.f;
#pragma unroll
            for (int w2 = 0; w2 < 8; ++w2) ss += rsum[w2][quad * 4 + r];
            gm[r] = 1.0f / ss;
        }
#pragma unroll
        for (int f = 0; f < 8; ++f)
#pragma unroll
            for (int r = 0; r < 4; ++r)
                Pl[quad * 4 + r][w * 128 + f * 16 + l15] = (bf16_t)(s[f][r] * gm[r]);
        __syncthreads();

        // ---- T_h = P @ yn : this wave owns cols [w*96, +96); K-dim = m (1024)
        f32x4 t[6];
#pragma unroll
        for (int g = 0; g < 6; ++g) t[g] = fz;
        const bf16_t* yb0 = YNT + ynoff + (long)(w * 96 + l15) * 1024 + quad * 8;
#pragma unroll 4
        for (int ks = 0; ks < 32; ++ks) {
            const bf16x8 pa = *(const bf16x8*)(&Pl[l15][ks * 32 + quad * 8]);
#pragma unroll
            for (int g = 0; g < 6; ++g) {
                const bf16x8 yb = *(const bf16x8*)(yb0 + (long)g * 16 * 1024 + ks * 32);
                t[g] = mfma16(pa, yb, t[g]);
            }
        }
        // write T: Tb[trow0 + quad*4 + r][hl*768 + w*96 + g*16 + l15]
#pragma unroll
        for (int g = 0; g < 6; ++g)
#pragma unroll
            for (int r = 0; r < 4; ++r)
                Tb[(trow0 + quad * 4 + r) * 3072 + hl * 768 + w * 96 + g * 16 + l15] =
                    (bf16_t)t[g][r];
        __syncthreads();   // before next head overwrites Pl/rmax/rsum
    }
}

// ---------------------------------------------------------------- h_pre epilogue
__global__ __launch_bounds__(256)
void hpre_ep(const float* __restrict__ dx, const float* __restrict__ bvs,
             const bf16_t* __restrict__ xn, bf16_t* __restrict__ hp) {
    const long i = (long)blockIdx.x * 256 + threadIdx.x;   // grid covers 6291456
    const int e = (int)(i % 768);
    hp[i] = (bf16_t)(dx[i] + bvs[e] + (float)xn[i]);
}

// ---------------------------------------------------------------- output emit
__global__ __launch_bounds__(256)
void emit2(const bf16_t* __restrict__ a, const bf16_t* __restrict__ b,
           void* __restrict__ out, const int* __restrict__ flagp) {
    const int mode = *flagp;
    const long n = 6291456;
    const long stride = (long)gridDim.x * blockDim.x;
    for (long i = (long)blockIdx.x * blockDim.x + threadIdx.x; i < 2 * n; i += stride) {
        const bf16_t v = (i < n) ? a[i] : b[i - n];
        if (mode) ((float*)out)[i] = (float)v;
        else      ((bf16_t*)out)[i] = v;
    }
}

// ---------------------------------------------------------------- launch
extern "C" void kernel_launch(void* const* d_in, const int* in_sizes, int n_in,
                              void* d_out, int out_size, void* d_ws, size_t ws_size,
                              hipStream_t stream) {
    (void)in_sizes; (void)n_in; (void)out_size; (void)ws_size;

    const void* x    = d_in[0];
    const void* y    = d_in[1];
    const void* ln1g = d_in[2];
    const void* ln1b = d_in[3];
    const void* ln2g = d_in[4];
    const void* ln2b = d_in[5];
    const void* ln3g = d_in[6];
    const void* ln3b = d_in[7];
    const void* wq   = d_in[8];
    const void* bq   = d_in[9];
    const void* wk   = d_in[10];
    const void* bk   = d_in[11];
    const void* wv   = d_in[12];
    const void* bv   = d_in[13];
    const void* wi   = d_in[14];
    const void* bi   = d_in[15];
    const void* wo   = d_in[16];
    const void* bo   = d_in[17];

    // workspace layout (canonical bf16 unless noted), ~157.3 MB
    char* ws = (char*)d_ws;
    bf16_t* xn    = (bf16_t*)(ws + 0);           // 12,582,912
    bf16_t* ynb   = (bf16_t*)(ws + 12582912);    // 12,582,912 (output 1, kept till emit)
    bf16_t* ynT   = (bf16_t*)(ws + 25165824);    // 12,582,912
    bf16_t* qb    = (bf16_t*)(ws + 37748736);    // 12,582,912 (Q; later h_pre)
    bf16_t* kb    = (bf16_t*)(ws + 50331648);    // 12,582,912 (K; later hn)
    bf16_t* Tbuf  = (bf16_t*)(ws + 62914560);    // 8192 x 3072 = 50,331,648 (later mid)
    float*  dxf   = (float*) (ws + 113246208);   // 8192 x 768 x 4 = 25,165,824
    bf16_t* W2T   = (bf16_t*)(ws + 138412032);   // 768 x 9216 = 14,155,776
    bf16_t* wqT   = (bf16_t*)(ws + 152567808);   // 1,179,648
    bf16_t* wkT   = (bf16_t*)(ws + 153747456);
    bf16_t* wiT   = (bf16_t*)(ws + 154927104);
    bf16_t* woT   = (bf16_t*)(ws + 156106752);
    float*  bvs   = (float*) (ws + 157286400);   // 3,072
    int*    flag  = (int*)   (ws + 157290496);   // flag[0]=fp32 mode, flag[1]=0
    bf16_t* hpre  = qb;
    bf16_t* hn    = kb;
    bf16_t* mid   = Tbuf;
    bf16_t* res0  = xn;
    const int* F  = flag;
    const int* Z  = flag + 1;

    detect_dtype<<<1, 256, 0, stream>>>(x, flag);

    const dim3 tb(32, 8);
    transpose_cvt<<<dim3(24, 24, 1), tb, 0, stream>>>(wq, wqT, 768, 768, F);
    transpose_cvt<<<dim3(24, 24, 1), tb, 0, stream>>>(wk, wkT, 768, 768, F);
    transpose_cvt<<<dim3(24, 24, 1), tb, 0, stream>>>(wi, wiT, 768, 768, F);
    transpose_cvt<<<dim3(24, 24, 1), tb, 0, stream>>>(wo, woT, 768, 768, F);
    transpose_wv<<<dim3(24, 24, 12), tb, 0, stream>>>(wv, W2T, F);
    bvsum_k<<<3, 256, 0, stream>>>(bv, bvs, F);

    ln768<<<8192, 256, 0, stream>>>(x, xn, ln1g, ln1b, F, F);
    ln768<<<8192, 256, 0, stream>>>(y, ynb, ln2g, ln2b, F, F);
    transpose_cvt<<<dim3(24, 32, 8), tb, 0, stream>>>(ynb, ynT, 1024, 768, Z);

    // Q = xn @ wq + bq; K = yn @ wk + bk
    gemm_bt<<<dim3(6, 64), 256, 0, stream>>>(xn, wqT, qb, 768, 768, 768, 768,
                                             bq, F, nullptr, 0);
    gemm_bt<<<dim3(6, 64), 256, 0, stream>>>(ynb, wkT, kb, 768, 768, 768, 768,
                                             bk, F, nullptr, 0);

    // attention in 3 head-groups of 4: T = P@yn, then dx (+)= T @ W2^T
    for (int hg = 0; hg < 3; ++hg) {
        fused_T<<<1024, 512, 0, stream>>>(qb, kb, ynT, Tbuf, hg);
        gemm_acc<<<dim3(6, 64), 256, 0, stream>>>(Tbuf, W2T + hg * 3072, dxf,
                                                  3072, 3072, 9216, 768, hg == 0);
    }

    // h_pre = xn + dx + sum_h bv_h   (qb dead -> reuse)
    hpre_ep<<<24576, 256, 0, stream>>>(dxf, bvs, xn, hpre);

    ln768<<<8192, 256, 0, stream>>>(hpre, hn, ln3g, ln3b, Z, F);

    gemm_bt<<<dim3(6, 64), 256, 0, stream>>>(hn, wiT, mid, 768, 768, 768, 768,
                                             bi, F, nullptr, 1);
    gemm_bt<<<dim3(6, 64), 256, 0, stream>>>(mid, woT, res0, 768, 768, 768, 768,
                                             bo, F, hn, 0);

    emit2<<<2048, 256, 0, stream>>>(res0, ynb, d_out, F);
}